// Round 5
// baseline (434.391 us; speedup 1.0000x reference)
//
#include <hip/hip_runtime.h>
#include <hip/hip_bf16.h>

#define E_ 8
#define D_ 1024
#define F_ 4096
#define S_ 2048
#define B_ 2
#define T_ 4096
#define CAP 1024
#define LN_EPS 1e-5f
#define NTAB 512

typedef __attribute__((ext_vector_type(8))) short short8;
typedef __attribute__((ext_vector_type(4))) float f32x4;

__device__ __forceinline__ unsigned short f2bf(float f) {
  __hip_bfloat16 h = __float2bfloat16(f);
  return *reinterpret_cast<unsigned short*>(&h);
}

// ---------- fused gating + LN + bucket scatter + out init (x + b2[e]) ----------
__global__ __launch_bounds__(256) void gate_ln_kernel(
    const float* __restrict__ x, const float* __restrict__ cent,
    const float* __restrict__ g_, const float* __restrict__ bb_,
    const float* __restrict__ b2_,
    int* __restrict__ counts, int* __restrict__ perm,
    unsigned short* __restrict__ Xb, float* __restrict__ outp) {
  int token = blockIdx.x * 4 + (threadIdx.x >> 6);
  int lane = threadIdx.x & 63;
  int s = token & (S_ - 1), b = token >> 11;
  const float* xr = x + ((size_t)s * B_ + b) * D_;
  float* orow = outp + ((size_t)s * B_ + b) * D_;

  float v[16];
  float acc[E_];
#pragma unroll
  for (int e = 0; e < E_; ++e) acc[e] = 0.f;
  float sum = 0.f, sq = 0.f;
#pragma unroll
  for (int c = 0; c < 4; ++c) {
    f32x4 xv = *(const f32x4*)(xr + c * 256 + lane * 4);
    v[c * 4 + 0] = xv.x; v[c * 4 + 1] = xv.y; v[c * 4 + 2] = xv.z; v[c * 4 + 3] = xv.w;
    sum += xv.x + xv.y + xv.z + xv.w;
    sq += xv.x * xv.x + xv.y * xv.y + xv.z * xv.z + xv.w * xv.w;
#pragma unroll
    for (int e = 0; e < E_; ++e) {
      f32x4 cv = *(const f32x4*)(cent + e * D_ + c * 256 + lane * 4);
      acc[e] += xv.x * cv.x + xv.y * cv.y + xv.z * cv.z + xv.w * cv.w;
    }
  }
#pragma unroll
  for (int off = 32; off > 0; off >>= 1) {
    sum += __shfl_down(sum, off);
    sq += __shfl_down(sq, off);
#pragma unroll
    for (int e = 0; e < E_; ++e) acc[e] += __shfl_down(acc[e], off);
  }
  int best = 0, slot = 0;
  if (lane == 0) {
    float bv = acc[0];
#pragma unroll
    for (int e = 1; e < E_; ++e) if (acc[e] > bv) { bv = acc[e]; best = e; }
    slot = atomicAdd(&counts[best], 1);
    perm[best * CAP + slot] = token;
  }
  best = __shfl(best, 0); slot = __shfl(slot, 0);
  sum = __shfl(sum, 0); sq = __shfl(sq, 0);
  float mu = sum * (1.f / D_);
  float var = sq * (1.f / D_) - mu * mu;
  float rstd = rsqrtf(var + LN_EPS);
  int e = best;
  unsigned short* dst = Xb + (size_t)(e * CAP + slot) * D_;
#pragma unroll
  for (int c = 0; c < 4; ++c) {
    int d = c * 256 + lane * 4;
    f32x4 gv = *(const f32x4*)(g_ + e * D_ + d);
    f32x4 bv = *(const f32x4*)(bb_ + e * D_ + d);
    f32x4 b2v = *(const f32x4*)(b2_ + e * D_ + d);
    ushort4 o;
    o.x = f2bf((v[c * 4 + 0] - mu) * rstd * gv.x + bv.x);
    o.y = f2bf((v[c * 4 + 1] - mu) * rstd * gv.y + bv.y);
    o.z = f2bf((v[c * 4 + 2] - mu) * rstd * gv.z + bv.z);
    o.w = f2bf((v[c * 4 + 3] - mu) * rstd * gv.w + bv.w);
    *(ushort4*)(dst + d) = o;
    f32x4 oi;
    oi.x = v[c * 4 + 0] + b2v.x; oi.y = v[c * 4 + 1] + b2v.y;
    oi.z = v[c * 4 + 2] + b2v.z; oi.w = v[c * 4 + 3] + b2v.w;
    *(f32x4*)(orow + d) = oi;
  }
}

// ---------- prefix + XCD-grouped schedule tables ----------
// entry pack: (e<<24)|(m<<16)|(n<<8)|kz ; -1 = empty
__global__ void prefix_kernel(const int* __restrict__ counts, int* __restrict__ offs,
                              int* __restrict__ tabF1, int* __restrict__ tabF2) {
  if (threadIdx.x != 0) return;
  int nb[E_];
  int s = 0;
  for (int e = 0; e < E_; ++e) {
    offs[e] = s;
    nb[e] = (counts[e] + 255) >> 8;
    s += counts[e];
  }
  offs[E_] = s;

  // FF1: groups (e, n 0..15), each with nb[e] m-entries -> same XCD (idx%8)
  {
    int q[8][64]; int ql[8] = {0, 0, 0, 0, 0, 0, 0, 0};
    int g = 0;
    for (int n = 0; n < 16; ++n)
      for (int e = 0; e < E_; ++e) {
        int x = g & 7; ++g;
        for (int m = 0; m < nb[e]; ++m)
          q[x][ql[x]++] = (e << 24) | (m << 16) | (n << 8);
      }
    for (int p = 0; p < 64; ++p)
      for (int x = 0; x < 8; ++x)
        tabF1[p * 8 + x] = (p < ql[x]) ? q[x][p] : -1;
  }
  // FF2: groups (e, n 0..3, kz 0..3)
  {
    int q[8][64]; int ql[8] = {0, 0, 0, 0, 0, 0, 0, 0};
    int g = 0;
    for (int kz = 0; kz < 4; ++kz)
      for (int n = 0; n < 4; ++n)
        for (int e = 0; e < E_; ++e) {
          int x = g & 7; ++g;
          for (int m = 0; m < nb[e]; ++m)
            q[x][ql[x]++] = (e << 24) | (m << 16) | (n << 8) | kz;
        }
    for (int p = 0; p < 64; ++p)
      for (int x = 0; x < 8; ++x)
        tabF2[p * 8 + x] = (p < ql[x]) ? q[x][p] : -1;
  }
}

// ---------- grouped GEMM: 256x256 tile, 8 waves, distance-2 pipeline ----------
// A[rows][K] bf16, W[E][K][N] fp32 (cvt->bf16 at load).
// MODE 0: H = relu(A*W1 + b1) -> bf16 compact   MODE 1: atomicAdd into out (split-K)
template <int K, int N, int MODE, int KSPLIT>
__global__ __launch_bounds__(512, 2) void moe_gemm_kernel(
    const unsigned short* __restrict__ A,
    const float* __restrict__ W,
    const float* __restrict__ bias,
    const int* __restrict__ counts,
    const int* __restrict__ offs,
    const int* __restrict__ tab,
    const int* __restrict__ perm,
    void* __restrict__ outp) {
  const int te = tab[blockIdx.x];
  if (te < 0) return;
  const int e = te >> 24;
  const int m0 = ((te >> 16) & 255) << 8;
  const int n0 = ((te >> 8) & 255) << 8;
  const int kz = te & 255;
  const int cnt = counts[e];
  const int aoff = (MODE == 0) ? e * CAP : offs[e];
  const int hoff = offs[e];
  const int kstart = kz * (K / KSPLIT);
  constexpr int NSTEP = (K / KSPLIT) / 32;
  static_assert(NSTEP >= 4 && (NSTEP % 2) == 0, "NSTEP must be even >= 4");

  const int tid = threadIdx.x;
  const int lane = tid & 63;
  const int wave = tid >> 6;

  // per buffer: [oct 0..3][row/col 0..255][8 bf16] = 8192 shorts (16 KB)
  __shared__ __align__(16) unsigned short lA[2][8192];
  __shared__ __align__(16) unsigned short lB[2][8192];

  // A: thread covers cells (qa, ra) and (qa+2, ra)
  const int ra = tid & 255;
  const int qa = tid >> 8;  // 0..1
  const int arow = aoff + min(m0 + ra, cnt - 1);
  const unsigned short* asrc = A + (size_t)arow * K + kstart + qa * 8;
  // B: thread covers cells (ob, col) and (ob+2, col)
  const int col = tid & 255;
  const int ob = tid >> 8;  // 0..1
  const float* wsrc = W + (size_t)e * K * N + (size_t)(kstart + ob * 8) * N + n0 + col;

  f32x4 acc[8][4] = {};
  const int wr = wave >> 2;   // 0..1
  const int wc = wave & 3;    // 0..3
  const int fr = lane & 15;
  const int fq = lane >> 4;

  // two named register slots (tile parity)
  short8 pA00, pA01, pA10, pA11;   // pA<slot><cell>
  short8 pB00, pB01, pB10, pB11;

#define LOADSLOT(TV, SL)                                                       \
  {                                                                            \
    const unsigned short* ap_ = asrc + (TV) * 32;                              \
    pA##SL##0 = *(const short8*)ap_;                                           \
    pA##SL##1 = *(const short8*)(ap_ + 16);                                    \
    const float* wp_ = wsrc + (size_t)(TV) * 32 * N;                           \
    short8 b0_, b1_;                                                           \
    _Pragma("unroll") for (int j = 0; j < 8; ++j) {                            \
      b0_[j] = (short)f2bf(wp_[(size_t)j * N]);                                \
      b1_[j] = (short)f2bf(wp_[(size_t)(16 + j) * N]);                         \
    }                                                                          \
    pB##SL##0 = b0_; pB##SL##1 = b1_;                                          \
  }

#define WRITESLOT(SL)                                                          \
  {                                                                            \
    *(short8*)&lA[SL][qa * 2048 + ra * 8] = pA##SL##0;                         \
    *(short8*)&lA[SL][(qa + 2) * 2048 + ra * 8] = pA##SL##1;                   \
    *(short8*)&lB[SL][ob * 2048 + col * 8] = pB##SL##0;                        \
    *(short8*)&lB[SL][(ob + 2) * 2048 + col * 8] = pB##SL##1;                  \
  }

  // prologue: tiles 0,1 -> slots 0,1; write slot0 -> buf0
  LOADSLOT(0, 0)
  LOADSLOT(1, 1)
  WRITESLOT(0)
  asm volatile("s_waitcnt lgkmcnt(0)" ::: "memory");
  __builtin_amdgcn_s_barrier();
  asm volatile("" ::: "memory");

#define STEP_BODY(TV, CUR, NXT)                                                \
  {                                                                            \
    const int tv_ = (TV);                                                      \
    if (tv_ + 2 < NSTEP) LOADSLOT(tv_ + 2, CUR)                                \
    if (tv_ + 1 < NSTEP) WRITESLOT(NXT)                                        \
    short8 af_[8], bf_[4];                                                     \
    _Pragma("unroll") for (int m = 0; m < 8; ++m)                              \
        af_[m] = *(const short8*)&lA[CUR][fq * 2048 +                          \
                                          (wr * 128 + m * 16 + fr) * 8];       \
    _Pragma("unroll") for (int n = 0; n < 4; ++n)                              \
        bf_[n] = *(const short8*)&lB[CUR][fq * 2048 +                          \
                                          (wc * 64 + n * 16 + fr) * 8];        \
    __builtin_amdgcn_s_setprio(1);                                             \
    _Pragma("unroll") for (int m = 0; m < 8; ++m)                              \
        _Pragma("unroll") for (int n = 0; n < 4; ++n)                          \
            acc[m][n] = __builtin_amdgcn_mfma_f32_16x16x32_bf16(               \
                af_[m], bf_[n], acc[m][n], 0, 0, 0);                           \
    __builtin_amdgcn_s_setprio(0);                                             \
    asm volatile("s_waitcnt lgkmcnt(0)" ::: "memory");                         \
    __builtin_amdgcn_s_barrier();                                              \
    asm volatile("" ::: "memory");                                             \
  }

  for (int t = 0; t < NSTEP; t += 2) {
    STEP_BODY(t, 0, 1)
    STEP_BODY(t + 1, 1, 0)
  }
#undef STEP_BODY
#undef LOADSLOT
#undef WRITESLOT

  if (MODE == 0) {
    unsigned short* Hout = (unsigned short*)outp;
    float bv[4];
#pragma unroll
    for (int n = 0; n < 4; ++n) bv[n] = bias[e * N + n0 + wc * 64 + n * 16 + fr];
#pragma unroll
    for (int m = 0; m < 8; ++m) {
#pragma unroll
      for (int j = 0; j < 4; ++j) {
        int rg = m0 + wr * 128 + m * 16 + fq * 4 + j;
        if (rg < cnt) {
          size_t base = (size_t)(hoff + rg) * N;
#pragma unroll
          for (int n = 0; n < 4; ++n) {
            float hv = acc[m][n][j] + bv[n];
            hv = fmaxf(hv, 0.f);
            Hout[base + n0 + wc * 64 + n * 16 + fr] = f2bf(hv);
          }
        }
      }
    }
  } else {
    float* Out = (float*)outp;
#pragma unroll
    for (int m = 0; m < 8; ++m) {
#pragma unroll
      for (int j = 0; j < 4; ++j) {
        int rg = m0 + wr * 128 + m * 16 + fq * 4 + j;
        if (rg < cnt) {
          int token = perm[e * CAP + rg];
          size_t base = ((size_t)(token & (S_ - 1)) * B_ + (token >> 11)) * (size_t)D_;
#pragma unroll
          for (int n = 0; n < 4; ++n)
            atomicAdd(&Out[base + n0 + wc * 64 + n * 16 + fr], acc[m][n][j]);
        }
      }
    }
  }
}

extern "C" void kernel_launch(void* const* d_in, const int* in_sizes, int n_in,
                              void* d_out, int out_size, void* d_ws, size_t ws_size,
                              hipStream_t stream) {
  const float* x    = (const float*)d_in[0];
  const float* cent = (const float*)d_in[1];
  const float* lng  = (const float*)d_in[2];
  const float* lnb  = (const float*)d_in[3];
  const float* W1   = (const float*)d_in[4];
  const float* b1   = (const float*)d_in[5];
  const float* W2   = (const float*)d_in[6];
  const float* b2   = (const float*)d_in[7];
  float* out = (float*)d_out;

  char* ws = (char*)d_ws;
  int* counts = (int*)(ws + 0);          // 8 ints
  int* offs   = (int*)(ws + 64);         // 9 ints
  int* tabF1  = (int*)(ws + 256);        // 512 ints
  int* tabF2  = (int*)(ws + 2560);       // 512 ints
  int* perm   = (int*)(ws + 8192);       // [E][CAP] ints, 32KB
  unsigned short* Xb = (unsigned short*)(ws + ((size_t)1 << 18)); // [E][CAP][D] bf16, 16MB
  unsigned short* H  = (unsigned short*)(ws + ((size_t)1 << 25)); // [T][F] bf16 compact, 32MB

  if (ws_size < ((size_t)1 << 26)) return;  // need 64MB scratch

  hipMemsetAsync(counts, 0, 64, stream);
  gate_ln_kernel<<<T_ / 4, 256, 0, stream>>>(x, cent, lng, lnb, b2, counts, perm, Xb, out);
  prefix_kernel<<<1, 64, 0, stream>>>(counts, offs, tabF1, tabF2);
  // FF1: H = relu(Xb * W1 + b1)
  moe_gemm_kernel<D_, F_, 0, 1><<<NTAB, 512, 0, stream>>>(
      Xb, W1, b1, counts, offs, tabF1, perm, (void*)H);
  // FF2: out += H * W2 (split-K=4; out pre-initialized with x + b2)
  moe_gemm_kernel<F_, D_, 1, 4><<<NTAB, 512, 0, stream>>>(
      H, W2, nullptr, counts, offs, tabF2, perm, (void*)out);
}